// Round 6
// baseline (148.825 us; speedup 1.0000x reference)
//
#include <hip/hip_runtime.h>
#include <cmath>

// act: (4, 4096, 4096) float32, GROUP_SIZE = 32
#define NELEM     (4ull * 4096ull * 4096ull)   // 67108864
#define NV4       (NELEM / 4ull)               // 16777216 float4s
#define NGROUPS   128

#define GRID      2048
#define BLK       256
#define NTHREADS  ((size_t)GRID * BLK)          // 524288 (multiple of 1024)
#define ITERS     ((int)(NV4 / NTHREADS))       // 32

typedef float v4f __attribute__((ext_vector_type(4)));

#define ABS4MAX(v) fmaxf(fmaxf(fabsf(v.x), fabsf(v.y)), fmaxf(fabsf(v.z), fabsf(v.w)))

// ---------------------------------------------------------------------------
// Pass 1: per-block abs-max via LDS, then device-scope global atomicMax into
// gmax[128] (zeroed by a memset node each call). Block bid covers float4
// columns (bid&3)*256..+255 of each 1024-float4 row -> its threads touch
// exactly 32 groups, group index invariant per thread. Caching loads on
// purpose: they warm L3 for pass 2's re-read.
__global__ void __launch_bounds__(BLK)
pass1_max(const float4* __restrict__ in, unsigned int* __restrict__ gmax) {
    __shared__ unsigned int smax[32];
    const int tid = threadIdx.x;
    const int bid = blockIdx.x;
    const int res = bid & 3;
    const int l   = tid >> 3;                    // local group 0..31

    if (tid < 32) smax[tid] = 0u;
    __syncthreads();

    const size_t idx = (size_t)bid * BLK + tid;
    float m = 0.0f;
    for (int t = 0; t < ITERS; t += 8) {         // 8 independent loads in flight
        float4 v0 = in[idx + (size_t)(t + 0) * NTHREADS];
        float4 v1 = in[idx + (size_t)(t + 1) * NTHREADS];
        float4 v2 = in[idx + (size_t)(t + 2) * NTHREADS];
        float4 v3 = in[idx + (size_t)(t + 3) * NTHREADS];
        float4 v4 = in[idx + (size_t)(t + 4) * NTHREADS];
        float4 v5 = in[idx + (size_t)(t + 5) * NTHREADS];
        float4 v6 = in[idx + (size_t)(t + 6) * NTHREADS];
        float4 v7 = in[idx + (size_t)(t + 7) * NTHREADS];
        float m0 = fmaxf(ABS4MAX(v0), ABS4MAX(v1));
        float m1 = fmaxf(ABS4MAX(v2), ABS4MAX(v3));
        float m2 = fmaxf(ABS4MAX(v4), ABS4MAX(v5));
        float m3 = fmaxf(ABS4MAX(v6), ABS4MAX(v7));
        m = fmaxf(m, fmaxf(fmaxf(m0, m1), fmaxf(m2, m3)));
    }
    atomicMax(&smax[l], __float_as_uint(m));     // non-neg floats order as uints
    __syncthreads();
    if (tid < 32)
        atomicMax(&gmax[res * 32 + tid], smax[tid]);   // device-scope (global)
}

// ---------------------------------------------------------------------------
// Pass 2: prologue derives exact pow-2 scales from gmax (512 B, broadcast via
// caches; kernel-boundary coherence makes this safe), then quantizes with
// 8-deep load batching + non-temporal stores (don't evict L3-resident input).
// rintf = round-half-even = jnp.round; all scale factors are powers of two
// -> bit-exact vs the numpy reference. Blocks 0..3 also emit the exps tail.
__global__ void __launch_bounds__(BLK)
pass2_quant(const float4* __restrict__ in, float4* __restrict__ out,
            const unsigned int* __restrict__ gmax,
            float* __restrict__ exps_out) {
    __shared__ float2 ssc[32];
    const int tid = threadIdx.x;
    const int bid = blockIdx.x;
    const int res = bid & 3;
    const int l   = tid >> 3;

    if (tid < 32) {
        const float mf = __uint_as_float(gmax[res * 32 + tid]);
        int e = 0;
        if (mf > 0.0f) { int e2; (void)frexpf(mf, &e2); e = e2 - 1; }  // exact floor(log2)
        ssc[tid] = make_float2(ldexpf(1.0f, e - 3),   // s/8
                               ldexpf(1.0f, -e));     // 1/s
        if (bid < 4) exps_out[res * 32 + tid] = (float)e;
    }
    __syncthreads();

    const float qstep = ssc[l].x;
    const float inv_s = ssc[l].y;
    const size_t idx = (size_t)bid * BLK + tid;

    #define Q1(v, q)                                                                 \
        q.x = copysignf(rintf(fminf(fabsf(v.x) * inv_s, 1.0f) * 8.0f) * qstep, v.x); \
        q.y = copysignf(rintf(fminf(fabsf(v.y) * inv_s, 1.0f) * 8.0f) * qstep, v.y); \
        q.z = copysignf(rintf(fminf(fabsf(v.z) * inv_s, 1.0f) * 8.0f) * qstep, v.z); \
        q.w = copysignf(rintf(fminf(fabsf(v.w) * inv_s, 1.0f) * 8.0f) * qstep, v.w);

    for (int t = 0; t < ITERS; t += 8) {
        const size_t i0 = idx + (size_t)(t + 0) * NTHREADS;
        const size_t i1 = idx + (size_t)(t + 1) * NTHREADS;
        const size_t i2 = idx + (size_t)(t + 2) * NTHREADS;
        const size_t i3 = idx + (size_t)(t + 3) * NTHREADS;
        const size_t i4 = idx + (size_t)(t + 4) * NTHREADS;
        const size_t i5 = idx + (size_t)(t + 5) * NTHREADS;
        const size_t i6 = idx + (size_t)(t + 6) * NTHREADS;
        const size_t i7 = idx + (size_t)(t + 7) * NTHREADS;
        float4 v0 = in[i0]; float4 v1 = in[i1]; float4 v2 = in[i2]; float4 v3 = in[i3];
        float4 v4 = in[i4]; float4 v5 = in[i5]; float4 v6 = in[i6]; float4 v7 = in[i7];
        v4f q;
        Q1(v0, q) __builtin_nontemporal_store(q, (v4f*)&out[i0]);
        Q1(v1, q) __builtin_nontemporal_store(q, (v4f*)&out[i1]);
        Q1(v2, q) __builtin_nontemporal_store(q, (v4f*)&out[i2]);
        Q1(v3, q) __builtin_nontemporal_store(q, (v4f*)&out[i3]);
        Q1(v4, q) __builtin_nontemporal_store(q, (v4f*)&out[i4]);
        Q1(v5, q) __builtin_nontemporal_store(q, (v4f*)&out[i5]);
        Q1(v6, q) __builtin_nontemporal_store(q, (v4f*)&out[i6]);
        Q1(v7, q) __builtin_nontemporal_store(q, (v4f*)&out[i7]);
    }
    #undef Q1
}

// ---------------------------------------------------------------------------
extern "C" void kernel_launch(void* const* d_in, const int* in_sizes, int n_in,
                              void* d_out, int out_size, void* d_ws, size_t ws_size,
                              hipStream_t stream) {
    const float* act = (const float*)d_in[0];
    float* q_out    = (float*)d_out;
    float* exps_out = q_out + NELEM;                        // 128 floats at tail
    unsigned int* gmax = (unsigned int*)d_ws;               // 128 * 4 B

    // ws is poisoned 0xAA and never re-poisoned between replays: zero each call.
    hipMemsetAsync(gmax, 0, NGROUPS * sizeof(unsigned int), stream);

    pass1_max<<<GRID, BLK, 0, stream>>>((const float4*)act, gmax);
    pass2_quant<<<GRID, BLK, 0, stream>>>((const float4*)act, (float4*)q_out,
                                          gmax, exps_out);
}

// Round 8
// 140.637 us; speedup vs baseline: 1.0582x; 1.0582x over previous
//
#include <hip/hip_runtime.h>
#include <cmath>

// act: (4, 4096, 4096) float32, GROUP_SIZE = 32
#define NELEM     (4ull * 4096ull * 4096ull)   // 67108864
#define NV4       (NELEM / 4ull)               // 16777216 float4s
#define NGROUPS   128

#define GRID      2048
#define BLK       256
#define NTHREADS  ((size_t)GRID * BLK)          // 524288 (multiple of 1024)
#define ITERS     ((int)(NV4 / NTHREADS))       // 32

typedef float v4f __attribute__((ext_vector_type(4)));
#define ABS4MAX(v) fmaxf(fmaxf(fabsf(v.x), fabsf(v.y)), fmaxf(fabsf(v.z), fabsf(v.w)))

// ---------------------------------------------------------------------------
// Pass 1: per-block abs-max via LDS -> device-scope global atomicMax into
// gmax[128] (zeroed by the memset node each call). Block bid covers float4
// columns (bid&3)*256..+255 of each 1024-float4 row -> exactly 32 groups,
// per-thread group index loop-invariant. SIMPLE loop (R4/R6 proved explicit
// deep batching hurts: TLP from 32 waves/CU supplies the MLP). Caching loads
// on purpose: they warm L3 for pass 2's re-read (proven fully L3-absorbed).
__global__ void __launch_bounds__(BLK)
pass1_max(const float4* __restrict__ in, unsigned int* __restrict__ gmax) {
    __shared__ unsigned int smax[32];
    const int tid = threadIdx.x;
    const int bid = blockIdx.x;
    const int res = bid & 3;
    const int l   = tid >> 3;                    // local group 0..31

    if (tid < 32) smax[tid] = 0u;
    __syncthreads();

    const size_t idx = (size_t)bid * BLK + tid;
    float m = 0.0f;
    #pragma unroll 4
    for (int t = 0; t < ITERS; ++t) {
        float4 v = in[idx + (size_t)t * NTHREADS];
        m = fmaxf(m, ABS4MAX(v));
    }
    atomicMax(&smax[l], __float_as_uint(m));     // non-neg floats order as uints
    __syncthreads();
    if (tid < 32)
        atomicMax(&gmax[res * 32 + tid], smax[tid]);   // device-scope
}

// ---------------------------------------------------------------------------
// Pass 2: 512 B prologue derives exact pow-2 scales from gmax (safe across
// the kernel boundary), then simple-loop quantize + non-temporal stores
// (keep the input L3-resident). q = copysign(rint(min(|a|*(8/s),8))*(s/8), a)
// -- algebraically identical to the reference (8/s is an exact power of 2),
// rintf = v_rndne = round-half-even = jnp.round -> bit-exact vs numpy.
__global__ void __launch_bounds__(BLK)
pass2_quant(const float4* __restrict__ in, float4* __restrict__ out,
            const unsigned int* __restrict__ gmax,
            float* __restrict__ exps_out) {
    __shared__ float2 ssc[32];
    const int tid = threadIdx.x;
    const int bid = blockIdx.x;
    const int res = bid & 3;
    const int l   = tid >> 3;

    if (tid < 32) {
        const float mf = __uint_as_float(gmax[res * 32 + tid]);
        int e = 0;
        if (mf > 0.0f) { int e2; (void)frexpf(mf, &e2); e = e2 - 1; }  // exact floor(log2)
        ssc[tid] = make_float2(ldexpf(1.0f, e - 3),    // qstep = s/8
                               ldexpf(1.0f, 3 - e));   // inv_s8 = 8/s
        if (bid < 4) exps_out[res * 32 + tid] = (float)e;
    }
    __syncthreads();

    const float qstep  = ssc[l].x;
    const float inv_s8 = ssc[l].y;
    const size_t idx = (size_t)bid * BLK + tid;

    #pragma unroll 4
    for (int t = 0; t < ITERS; ++t) {
        const size_t i = idx + (size_t)t * NTHREADS;
        float4 v = in[i];
        v4f q;
        q.x = copysignf(rintf(fminf(fabsf(v.x) * inv_s8, 8.0f)) * qstep, v.x);
        q.y = copysignf(rintf(fminf(fabsf(v.y) * inv_s8, 8.0f)) * qstep, v.y);
        q.z = copysignf(rintf(fminf(fabsf(v.z) * inv_s8, 8.0f)) * qstep, v.z);
        q.w = copysignf(rintf(fminf(fabsf(v.w) * inv_s8, 8.0f)) * qstep, v.w);
        __builtin_nontemporal_store(q, (v4f*)&out[i]);
    }
}

// ---------------------------------------------------------------------------
extern "C" void kernel_launch(void* const* d_in, const int* in_sizes, int n_in,
                              void* d_out, int out_size, void* d_ws, size_t ws_size,
                              hipStream_t stream) {
    const float* act = (const float*)d_in[0];
    float* q_out    = (float*)d_out;
    float* exps_out = q_out + NELEM;                        // 128 floats at tail
    unsigned int* gmax = (unsigned int*)d_ws;               // 128 * 4 B

    // ws is poisoned 0xAA and never re-poisoned between replays: zero each call.
    hipMemsetAsync(gmax, 0, NGROUPS * sizeof(unsigned int), stream);

    pass1_max<<<GRID, BLK, 0, stream>>>((const float4*)act, gmax);
    pass2_quant<<<GRID, BLK, 0, stream>>>((const float4*)act, (float4*)q_out,
                                          gmax, exps_out);
}

// Round 9
// 136.413 us; speedup vs baseline: 1.0910x; 1.0310x over previous
//
#include <hip/hip_runtime.h>
#include <cmath>

// act: (4, 4096, 4096) float32, GROUP_SIZE = 32
#define NELEM      (4ull * 4096ull * 4096ull)   // 67108864
#define NV4        (NELEM / 4ull)               // 16777216 float4s
#define NGROUPS    128                          // 4096 / 32
#define P1_BLOCKS  512
#define P1_THREADS 1024                         // 512*1024 = 524288 (mult of 1024)

typedef float v4f __attribute__((ext_vector_type(4)));
#define ABS4MAX(v) fmaxf(fmaxf(fabsf(v.x), fabsf(v.y)), fmaxf(fabsf(v.z), fabsf(v.w)))

// ---------------------------------------------------------------------------
// Pass 1 (R2-proven): per-(block,group) partial abs-max. blockDim=1024 so each
// thread's group g = tid>>3 is fixed across grid-stride iters. No global
// atomics (R8 showed the 65K-atomic tail costs ~8 µs), no memset. Caching
// loads on purpose: they warm L3 for pass 2's re-read (proven L3-absorbed, R3).
__global__ void __launch_bounds__(P1_THREADS)
pass1_max(const float4* __restrict__ in, unsigned int* __restrict__ partials) {
    __shared__ unsigned int smax[NGROUPS];
    const int tid = threadIdx.x;
    if (tid < NGROUPS) smax[tid] = 0u;
    __syncthreads();

    const size_t idx    = (size_t)blockIdx.x * P1_THREADS + tid;
    const size_t stride = (size_t)P1_BLOCKS * P1_THREADS;   // 524288
    const int g = tid >> 3;                                 // 0..127

    float m = 0.0f;
    #pragma unroll 4
    for (size_t i = idx; i < NV4; i += stride) {            // 32 iters
        float4 v = in[i];
        m = fmaxf(m, ABS4MAX(v));
    }
    atomicMax(&smax[g], __float_as_uint(m));    // non-neg floats order as uints
    __syncthreads();
    if (tid < NGROUPS)
        partials[(size_t)blockIdx.x * NGROUPS + tid] = smax[tid];
}

// ---------------------------------------------------------------------------
// Mid (R2-proven): reduce 512x128 partials (256 KB, cache-resident) -> exps +
// per-group {qstep = s/8, inv_s8 = 8/s}, all exact powers of two.
__global__ void __launch_bounds__(1024)
reduce_scales(const unsigned int* __restrict__ partials,
              float* __restrict__ exps_out, float2* __restrict__ scales) {
    __shared__ unsigned int red[NGROUPS];
    const int tid = threadIdx.x;
    if (tid < NGROUPS) red[tid] = 0u;
    __syncthreads();

    const int g = tid & 127;
    const int c = tid >> 7;                 // 8 chunks of 64 blocks
    unsigned int m = 0u;
    #pragma unroll 8
    for (int b = c * 64; b < c * 64 + 64; ++b)
        m = max(m, partials[(size_t)b * NGROUPS + g]);
    atomicMax(&red[g], m);
    __syncthreads();

    if (tid < NGROUPS) {
        const float mf = __uint_as_float(red[tid]);
        int e = 0;
        if (mf > 0.0f) {
            int e2;
            (void)frexpf(mf, &e2);          // mf = f * 2^e2, f in [0.5,1)
            e = e2 - 1;                     // exact floor(log2(mf))
        }
        exps_out[tid] = (float)e;
        scales[tid] = make_float2(ldexpf(1.0f, e - 3),   // qstep = s/8
                                  ldexpf(1.0f, 3 - e));  // inv_s8 = 8/s
    }
}

// ---------------------------------------------------------------------------
// Pass 2: q = copysign(rint(min(|a|*(8/s), 8)) * (s/8), a) — algebraically
// identical to the reference (8/s, s/8 exact powers of two); rintf = v_rndne
// = round-half-even = jnp.round -> bit-exact vs numpy.
// NT LOADS: the read stream hits L3 (proven R3) and would only pollute each
// XCD's 4 MB L2 — mark evict-first. NT STORES: keep the input L3-resident.
__global__ void __launch_bounds__(256)
pass2_quant(const float4* __restrict__ in, float4* __restrict__ out,
            const float2* __restrict__ scales) {
    __shared__ float2 ssc[32];
    const int tid = threadIdx.x;
    const int bid = blockIdx.x;
    const int res = bid & 3;                // quarter of the 1024-f4 row
    const int l   = tid >> 3;               // local group 0..31
    if (tid < 32) ssc[tid] = scales[res * 32 + tid];
    __syncthreads();

    const float qstep  = ssc[l].x;
    const float inv_s8 = ssc[l].y;
    const size_t idx    = (size_t)bid * 256 + tid;
    const size_t stride = (size_t)2048 * 256;               // 524288

    #pragma unroll 4
    for (size_t i = idx; i < NV4; i += stride) {            // 32 iters
        v4f v = __builtin_nontemporal_load((const v4f*)&in[i]);
        v4f q;
        q.x = copysignf(rintf(fminf(fabsf(v.x) * inv_s8, 8.0f)) * qstep, v.x);
        q.y = copysignf(rintf(fminf(fabsf(v.y) * inv_s8, 8.0f)) * qstep, v.y);
        q.z = copysignf(rintf(fminf(fabsf(v.z) * inv_s8, 8.0f)) * qstep, v.z);
        q.w = copysignf(rintf(fminf(fabsf(v.w) * inv_s8, 8.0f)) * qstep, v.w);
        __builtin_nontemporal_store(q, (v4f*)&out[i]);
    }
}

// ---------------------------------------------------------------------------
extern "C" void kernel_launch(void* const* d_in, const int* in_sizes, int n_in,
                              void* d_out, int out_size, void* d_ws, size_t ws_size,
                              hipStream_t stream) {
    const float* act = (const float*)d_in[0];
    float* q_out    = (float*)d_out;
    float* exps_out = q_out + NELEM;                        // 128 floats at tail

    unsigned int* partials = (unsigned int*)d_ws;           // 512*128*4 = 256 KB
    float2* scales = (float2*)((char*)d_ws + P1_BLOCKS * NGROUPS * sizeof(unsigned int));

    // All partials/scales slots are rewritten before read each call -> no
    // memset needed, poison-safe.
    pass1_max<<<P1_BLOCKS, P1_THREADS, 0, stream>>>((const float4*)act, partials);
    reduce_scales<<<1, 1024, 0, stream>>>(partials, exps_out, scales);
    pass2_quant<<<2048, 256, 0, stream>>>((const float4*)act, (float4*)q_out, scales);
}

// Round 10
// 131.449 us; speedup vs baseline: 1.1322x; 1.0378x over previous
//
#include <hip/hip_runtime.h>
#include <cmath>

// act: (4, 4096, 4096) float32, GROUP_SIZE = 32
#define NELEM      (4ull * 4096ull * 4096ull)   // 67108864
#define NV4        (NELEM / 4ull)               // 16777216 float4s
#define NGROUPS    128                          // 4096 / 32
#define P1_BLOCKS  512
#define P1_THREADS 1024                         // 512*1024 = 524288 (mult of 1024)

typedef float v4f __attribute__((ext_vector_type(4)));
#define ABS4MAX(v) fmaxf(fmaxf(fabsf(v.x), fabsf(v.y)), fmaxf(fabsf(v.z), fabsf(v.w)))

// ---------------------------------------------------------------------------
// Pass 1 (champion R2 config): per-(block,group) partial abs-max.
// blockDim=1024 -> each thread's group g = tid>>3 fixed across grid-stride
// iters; 512 blocks = 2 blocks/CU = 32 waves/CU (full occupancy).
// No global atomics (R8: 65K-atomic tail costs ~8 µs), no memset.
// PLAIN caching loads on purpose: they warm the 256 MB Infinity Cache so
// pass 2's re-read is L3-served (proven R3: fused-kernel FETCH = 256 MB
// total). NT loads here or in pass 2 bypass L3 and regress (R9: +3.5 µs).
__global__ void __launch_bounds__(P1_THREADS)
pass1_max(const float4* __restrict__ in, unsigned int* __restrict__ partials) {
    __shared__ unsigned int smax[NGROUPS];
    const int tid = threadIdx.x;
    if (tid < NGROUPS) smax[tid] = 0u;
    __syncthreads();

    const size_t idx    = (size_t)blockIdx.x * P1_THREADS + tid;
    const size_t stride = (size_t)P1_BLOCKS * P1_THREADS;   // 524288
    const int g = tid >> 3;                                 // 0..127

    float m = 0.0f;
    // Simple loop: explicit deep load-batching regressed (R4 +5 µs @depth4,
    // R6 +16 µs @depth8) — TLP from 32 waves/CU supplies the MLP.
    #pragma unroll 4
    for (size_t i = idx; i < NV4; i += stride) {            // 32 iters
        float4 v = in[i];
        m = fmaxf(m, ABS4MAX(v));
    }
    atomicMax(&smax[g], __float_as_uint(m));    // non-neg floats order as uints
    __syncthreads();
    if (tid < NGROUPS)
        partials[(size_t)blockIdx.x * NGROUPS + tid] = smax[tid];
}

// ---------------------------------------------------------------------------
// Mid: reduce 512x128 partials (256 KB, cache-resident, ~2-3 µs incl. launch)
// -> exps + per-group {qstep = s/8, inv_s8 = 8/s}, all exact powers of two.
// Kernel boundary provides the cross-XCD coherence the R5/R7 fused attempts
// lacked.
__global__ void __launch_bounds__(1024)
reduce_scales(const unsigned int* __restrict__ partials,
              float* __restrict__ exps_out, float2* __restrict__ scales) {
    __shared__ unsigned int red[NGROUPS];
    const int tid = threadIdx.x;
    if (tid < NGROUPS) red[tid] = 0u;
    __syncthreads();

    const int g = tid & 127;
    const int c = tid >> 7;                 // 8 chunks of 64 blocks
    unsigned int m = 0u;
    #pragma unroll 8
    for (int b = c * 64; b < c * 64 + 64; ++b)
        m = max(m, partials[(size_t)b * NGROUPS + g]);
    atomicMax(&red[g], m);
    __syncthreads();

    if (tid < NGROUPS) {
        const float mf = __uint_as_float(red[tid]);
        int e = 0;
        if (mf > 0.0f) {
            int e2;
            (void)frexpf(mf, &e2);          // mf = f * 2^e2, f in [0.5,1)
            e = e2 - 1;                     // exact floor(log2(mf))
        }
        exps_out[tid] = (float)e;
        scales[tid] = make_float2(ldexpf(1.0f, e - 3),   // qstep = s/8
                                  ldexpf(1.0f, 3 - e));  // inv_s8 = 8/s
    }
}

// ---------------------------------------------------------------------------
// Pass 2: q = copysign(rint(min(|a|*(8/s), 8)) * (s/8), a) — algebraically
// identical to the reference (8/s, s/8 exact powers of two); rintf = v_rndne
// = round-half-even = jnp.round -> bit-exact vs numpy.
// PLAIN loads (L3-served). NT STORES: the session's key win — the output
// stream must not evict the L3-resident input (R1->R2 evidence).
__global__ void __launch_bounds__(256)
pass2_quant(const float4* __restrict__ in, float4* __restrict__ out,
            const float2* __restrict__ scales) {
    __shared__ float2 ssc[32];
    const int tid = threadIdx.x;
    const int bid = blockIdx.x;
    const int res = bid & 3;                // quarter of the 1024-f4 row
    const int l   = tid >> 3;               // local group 0..31
    if (tid < 32) ssc[tid] = scales[res * 32 + tid];
    __syncthreads();

    const float qstep  = ssc[l].x;
    const float inv_s8 = ssc[l].y;
    const size_t idx    = (size_t)bid * 256 + tid;
    const size_t stride = (size_t)2048 * 256;               // 524288

    #pragma unroll 4
    for (size_t i = idx; i < NV4; i += stride) {            // 32 iters
        float4 v = in[i];
        v4f q;
        q.x = copysignf(rintf(fminf(fabsf(v.x) * inv_s8, 8.0f)) * qstep, v.x);
        q.y = copysignf(rintf(fminf(fabsf(v.y) * inv_s8, 8.0f)) * qstep, v.y);
        q.z = copysignf(rintf(fminf(fabsf(v.z) * inv_s8, 8.0f)) * qstep, v.z);
        q.w = copysignf(rintf(fminf(fabsf(v.w) * inv_s8, 8.0f)) * qstep, v.w);
        __builtin_nontemporal_store(q, (v4f*)&out[i]);
    }
}

// ---------------------------------------------------------------------------
extern "C" void kernel_launch(void* const* d_in, const int* in_sizes, int n_in,
                              void* d_out, int out_size, void* d_ws, size_t ws_size,
                              hipStream_t stream) {
    const float* act = (const float*)d_in[0];
    float* q_out    = (float*)d_out;
    float* exps_out = q_out + NELEM;                        // 128 floats at tail

    unsigned int* partials = (unsigned int*)d_ws;           // 512*128*4 = 256 KB
    float2* scales = (float2*)((char*)d_ws + P1_BLOCKS * NGROUPS * sizeof(unsigned int));

    // All partials/scales slots are rewritten before read each call -> no
    // memset needed, poison-safe.
    pass1_max<<<P1_BLOCKS, P1_THREADS, 0, stream>>>((const float4*)act, partials);
    reduce_scales<<<1, 1024, 0, stream>>>(partials, exps_out, scales);
    pass2_quant<<<2048, 256, 0, stream>>>((const float4*)act, (float4*)q_out, scales);
}